// Round 5
// baseline (1999.121 us; speedup 1.0000x reference)
//
#include <hip/hip_runtime.h>
#include <math.h>

#define BATCH 4096
#define HID   1024
#define KDIM  1024
#define NSTEP 15
#define KH    512        // split-K half depth

// Split-K GEMM: 256 threads (4 waves), tile TM=128 x TN=128, BK=16, 8x8 microtile.
// grid (32,8,2) = 512 blocks = 2048 waves = 2 waves/SIMD (latency hiding) at
// 1.0 FMA per LDS byte. Pair reduction + halt fused via atomic tile counters.
#define TM 128
#define TN 128
#define BK 16
#define LDT (TM + 4)     // 132

// init lists/accums + zero counters + repack W_ih (stride 1025) + flag column
__global__ __launch_bounds__(256) void setup_kernel(const float* __restrict__ W_ih,
                                                    float* __restrict__ Wp,
                                                    float* __restrict__ flagcol,
                                                    int* __restrict__ list0,
                                                    int* __restrict__ ctrs,   // counts[16]+pairx[256]+pair[15*256]+rowdone[15*32]
                                                    float* __restrict__ halt_accum,
                                                    float* __restrict__ tot_rem) {
    int idx = blockIdx.x * 256 + threadIdx.x;           // grid 4096 -> 1M threads
    Wp[idx] = W_ih[(size_t)(idx >> 10) * 1025 + (idx & 1023)];
    if (idx < BATCH) { list0[idx] = idx; halt_accum[idx] = 0.f; tot_rem[idx] = 0.f; }
    if (idx < KDIM) flagcol[idx] = W_ih[(size_t)idx * 1025 + 1024];
    if (idx < 16 + 256 + NSTEP * 256 + NSTEP * 32) ctrs[idx] = (idx == 0) ? BATCH : 0;
}

// mode 0: Cout[row] = A @ B^T + bias (x_base).  mode 1: recurrent step with
// tanh epilogue + fused halt on the last-finishing block of each row-tile.
__global__ __launch_bounds__(256, 2) void step_kernel(
    const float* __restrict__ A, const float* __restrict__ B,
    const float* __restrict__ bias,
    const float* __restrict__ xbase, const float* __restrict__ flagcol, float flag,
    const int* __restrict__ list, const int* __restrict__ pcount,
    float* __restrict__ Cout,
    float* __restrict__ partials, int* __restrict__ pairctr, int* __restrict__ rowdone,
    const float* __restrict__ W_halt, const float* __restrict__ b_halt,
    int* __restrict__ list_next, int* __restrict__ pcount_next,
    float* __restrict__ halt_accum, float* __restrict__ tot_rem,
    float* __restrict__ tot_h, float* __restrict__ steps_out,
    int stepnum, int first, int mode) {
    int count = pcount ? *pcount : BATCH;
    int rt = blockIdx.x, ct = blockIdx.y, z = blockIdx.z;
    int row0 = rt * TM;
    if (row0 >= count) return;
    int col0 = ct * TN;

    __shared__ float As[BK][LDT];
    __shared__ float Bs[BK][LDT];

    int t = threadIdx.x;
    int tx = t & 15, ty = t >> 4;
    int lane = t & 63, wid = t >> 6;

    // staging map: 128 rows x 4 kq-quads = 512 slots, 2 per thread (A and B)
    int r0s = (t) >> 2,        kq0 = t & 3;
    int r1s = (t + 256) >> 2,  kq1 = (t + 256) & 3;
    const float* ap0; const float* ap1;
    {
        int rr = row0 + r0s; int g = 0;
        if (rr < count) g = list ? list[rr] : rr;
        ap0 = A + (size_t)g * KDIM + z * KH + kq0 * 4;
        rr = row0 + r1s; g = 0;
        if (rr < count) g = list ? list[rr] : rr;
        ap1 = A + (size_t)g * KDIM + z * KH + kq1 * 4;
    }
    const float* bp0 = B + (size_t)(col0 + r0s) * KDIM + z * KH + kq0 * 4;
    const float* bp1 = B + (size_t)(col0 + r1s) * KDIM + z * KH + kq1 * 4;

    float acc[8][8];
#pragma unroll
    for (int i = 0; i < 8; i++)
#pragma unroll
        for (int j = 0; j < 8; j++) acc[i][j] = 0.f;

    float4 a0v = *(const float4*)(ap0);
    float4 a1v = *(const float4*)(ap1);
    float4 b0v = *(const float4*)(bp0);
    float4 b1v = *(const float4*)(bp1);

    for (int k0 = 0; k0 < KH; k0 += BK) {
        __syncthreads();
        As[kq0 * 4 + 0][r0s] = a0v.x; As[kq0 * 4 + 1][r0s] = a0v.y;
        As[kq0 * 4 + 2][r0s] = a0v.z; As[kq0 * 4 + 3][r0s] = a0v.w;
        As[kq1 * 4 + 0][r1s] = a1v.x; As[kq1 * 4 + 1][r1s] = a1v.y;
        As[kq1 * 4 + 2][r1s] = a1v.z; As[kq1 * 4 + 3][r1s] = a1v.w;
        Bs[kq0 * 4 + 0][r0s] = b0v.x; Bs[kq0 * 4 + 1][r0s] = b0v.y;
        Bs[kq0 * 4 + 2][r0s] = b0v.z; Bs[kq0 * 4 + 3][r0s] = b0v.w;
        Bs[kq1 * 4 + 0][r1s] = b1v.x; Bs[kq1 * 4 + 1][r1s] = b1v.y;
        Bs[kq1 * 4 + 2][r1s] = b1v.z; Bs[kq1 * 4 + 3][r1s] = b1v.w;
        __syncthreads();
        int kn = (k0 + BK < KH) ? (k0 + BK) : 0;       // prefetch next chunk
        a0v = *(const float4*)(ap0 + kn);
        a1v = *(const float4*)(ap1 + kn);
        b0v = *(const float4*)(bp0 + kn);
        b1v = *(const float4*)(bp1 + kn);
#pragma unroll
        for (int k = 0; k < BK; k++) {
            float4 x0 = *(const float4*)&As[k][ty * 4];
            float4 x1 = *(const float4*)&As[k][64 + ty * 4];
            float4 y0 = *(const float4*)&Bs[k][tx * 4];
            float4 y1 = *(const float4*)&Bs[k][64 + tx * 4];
            float a[8] = {x0.x, x0.y, x0.z, x0.w, x1.x, x1.y, x1.z, x1.w};
            float b[8] = {y0.x, y0.y, y0.z, y0.w, y1.x, y1.y, y1.z, y1.w};
#pragma unroll
            for (int i = 0; i < 8; i++)
#pragma unroll
                for (int j = 0; j < 8; j++)
                    acc[i][j] = fmaf(a[i], b[j], acc[i][j]);
        }
    }

    // ---- split-K pair protocol ----
    int pairidx = rt * 8 + ct;
    float* myslot = partials + ((size_t)(pairidx * 2 + z)) * (TM * TN);
#pragma unroll
    for (int i = 0; i < 8; i++) {
        int r = (i < 4) ? (ty * 4 + i) : (64 + ty * 4 + i - 4);
        *(float4*)(myslot + r * TN + tx * 4) =
            make_float4(acc[i][0], acc[i][1], acc[i][2], acc[i][3]);
        *(float4*)(myslot + r * TN + 64 + tx * 4) =
            make_float4(acc[i][4], acc[i][5], acc[i][6], acc[i][7]);
    }
    __threadfence();                                    // release partial
    __shared__ int amlast;
    if (t == 0) amlast = atomicAdd(&pairctr[pairidx], 1);
    __syncthreads();
    if (amlast == 0) return;                            // first of pair: done
    __threadfence();                                    // acquire other partial

    const float* os = partials + ((size_t)(pairidx * 2 + (1 - z))) * (TM * TN);
    float4 bia0 = *(const float4*)(bias + col0 + tx * 4);
    float4 bia1 = *(const float4*)(bias + col0 + 64 + tx * 4);
    float4 fc0, fc1;
    if (mode == 1) {
        fc0 = *(const float4*)(flagcol + col0 + tx * 4);
        fc1 = *(const float4*)(flagcol + col0 + 64 + tx * 4);
    }
#pragma unroll
    for (int i = 0; i < 8; i++) {
        int r = (i < 4) ? (ty * 4 + i) : (64 + ty * 4 + i - 4);
        int rr = row0 + r;
        if (rr >= count) continue;
        int grow = list ? list[rr] : rr;
        float4 p0 = *(const float4*)(os + r * TN + tx * 4);
        float4 p1 = *(const float4*)(os + r * TN + 64 + tx * 4);
        float4 v0 = make_float4(acc[i][0] + p0.x + bia0.x, acc[i][1] + p0.y + bia0.y,
                                acc[i][2] + p0.z + bia0.z, acc[i][3] + p0.w + bia0.w);
        float4 v1 = make_float4(acc[i][4] + p1.x + bia1.x, acc[i][5] + p1.y + bia1.y,
                                acc[i][6] + p1.z + bia1.z, acc[i][7] + p1.w + bia1.w);
        if (mode == 1) {
            const float* xr = xbase + (size_t)grow * KDIM + col0;
            float4 q0 = *(const float4*)(xr + tx * 4);
            float4 q1 = *(const float4*)(xr + 64 + tx * 4);
            v0.x = tanhf(v0.x + q0.x + flag * fc0.x);
            v0.y = tanhf(v0.y + q0.y + flag * fc0.y);
            v0.z = tanhf(v0.z + q0.z + flag * fc0.z);
            v0.w = tanhf(v0.w + q0.w + flag * fc0.w);
            v1.x = tanhf(v1.x + q1.x + flag * fc1.x);
            v1.y = tanhf(v1.y + q1.y + flag * fc1.y);
            v1.z = tanhf(v1.z + q1.z + flag * fc1.z);
            v1.w = tanhf(v1.w + q1.w + flag * fc1.w);
        }
        float* crow = Cout + (size_t)grow * KDIM + col0;
        *(float4*)(crow + tx * 4) = v0;
        *(float4*)(crow + 64 + tx * 4) = v1;
    }
    if (mode == 0) return;

    // ---- fused halt: last reducer of the row-tile handles its 128 rows ----
    __threadfence();                                    // release h tile
    __shared__ int hlast;
    if (t == 0) hlast = atomicAdd(&rowdone[rt], 1);
    __syncthreads();
    if (hlast != 7) return;
    __threadfence();                                    // acquire all h tiles

    int rend = (row0 + TM < count) ? (row0 + TM) : count;
    for (int r = row0 + wid; r < rend; r += 4) {        // wave per row
        int row = list[r];
        const float* hr = Cout + (size_t)row * HID;
        float dot = 0.f;
#pragma unroll
        for (int q = 0; q < 4; q++) {
            int c = q * 256 + lane * 4;
            float4 hv = *(const float4*)(hr + c);
            float4 wv = *(const float4*)(W_halt + c);
            dot += hv.x * wv.x + hv.y * wv.y + hv.z * wv.z + hv.w * wv.w;
        }
#pragma unroll
        for (int off = 32; off > 0; off >>= 1) dot += __shfl_down(dot, off);

        float combined = 0.f;
        if (lane == 0) {
            float p = 1.f / (1.f + expf(-(dot + b_halt[0])));
            float S = halt_accum[row] + p;
            halt_accum[row] = S;
            tot_rem[row] += p;
            bool ending = (S + p) > 0.99f;              // budget = 1 - PONDER_EPS
            if (ending) {
                combined = p + (1.f - S);
                steps_out[row] = (float)stepnum;
            } else {
                combined = p;
                int idx = atomicAdd(pcount_next, 1);
                list_next[idx] = row;
            }
        }
        combined = __shfl(combined, 0);

        float* th = tot_h + (size_t)row * HID;
#pragma unroll
        for (int q = 0; q < 4; q++) {
            int c = q * 256 + lane * 4;
            float4 hv = *(const float4*)(hr + c);
            float4 ov;
            if (first) {
                ov.x = combined * hv.x; ov.y = combined * hv.y;
                ov.z = combined * hv.z; ov.w = combined * hv.w;
            } else {
                ov = *(const float4*)(th + c);
                ov.x += combined * hv.x; ov.y += combined * hv.y;
                ov.z += combined * hv.z; ov.w += combined * hv.w;
            }
            *(float4*)(th + c) = ov;
        }
    }
}

// blocks 0..1023: survivors get (1 - halt_accum) * h_final, steps = 16.
// block 1024: ponder reduction.
__global__ __launch_bounds__(256) void epilogue_kernel(
    const float* __restrict__ h, const int* __restrict__ list,
    const int* __restrict__ pcount, const float* __restrict__ halt_accum,
    const float* __restrict__ tot_rem,
    float* __restrict__ tot_h, float* __restrict__ steps_out,
    float* __restrict__ ponder) {
    if (blockIdx.x == 1024) {
        __shared__ float red[4];
        int t = threadIdx.x;
        float v = 0.f;
#pragma unroll
        for (int i = 0; i < 16; i++) v += tot_rem[t + i * 256];
#pragma unroll
        for (int off = 32; off > 0; off >>= 1) v += __shfl_down(v, off);
        int lane = t & 63, wid = t >> 6;
        if (lane == 0) red[wid] = v;
        __syncthreads();
        if (t == 0) ponder[0] = (red[0] + red[1] + red[2] + red[3]) * (-0.01f / 4096.f);
        return;
    }
    int count = *pcount;
    int wid = threadIdx.x >> 6, lane = threadIdx.x & 63;
    int r = blockIdx.x * 4 + wid;
    if (r >= count) return;
    int row = list[r];
    float cmb = 1.f - halt_accum[row];
    if (lane == 0) steps_out[row] = 16.f;
    const float* hr = h + (size_t)row * HID;
    float* th = tot_h + (size_t)row * HID;
#pragma unroll
    for (int q = 0; q < 4; q++) {
        int c = q * 256 + lane * 4;
        float4 hv = *(const float4*)(hr + c);
        float4 ov = *(const float4*)(th + c);
        ov.x += cmb * hv.x; ov.y += cmb * hv.y;
        ov.z += cmb * hv.z; ov.w += cmb * hv.w;
        *(float4*)(th + c) = ov;
    }
}

extern "C" void kernel_launch(void* const* d_in, const int* in_sizes, int n_in,
                              void* d_out, int out_size, void* d_ws, size_t ws_size,
                              hipStream_t stream) {
    const float* inputs = (const float*)d_in[0];
    const float* hidden = (const float*)d_in[1];
    const float* W_ih   = (const float*)d_in[2];
    const float* b_ih   = (const float*)d_in[3];
    const float* W_hh   = (const float*)d_in[4];
    const float* b_hh   = (const float*)d_in[5];
    const float* W_halt = (const float*)d_in[6];
    const float* b_halt = (const float*)d_in[7];
    float* out = (float*)d_out;

    float* ws = (float*)d_ws;
    float* xbase = ws;                                   // 4M floats
    float* h0 = xbase + (size_t)BATCH * HID;             // 4M
    float* h1 = h0 + (size_t)BATCH * HID;                // 4M
    float* Wp = h1 + (size_t)BATCH * HID;                // 1M
    float* partials = Wp + (size_t)KDIM * KDIM;          // 32*8*2*16384 = 8.39M
    float* flagcol = partials + (size_t)32 * 8 * 2 * TM * TN;  // 1024
    float* halt_accum = flagcol + KDIM;                  // 4096
    float* tot_rem = halt_accum + BATCH;                 // 4096
    int* list0 = (int*)(tot_rem + BATCH);                // 4096
    int* list1 = list0 + BATCH;                          // 4096
    int* ctrs  = list1 + BATCH;                          // counts[16]+pairx[256]+pair[15*256]+rowdone[15*32]
    int* counts = ctrs;
    int* pairx = ctrs + 16;
    int* pairs = pairx + 256;
    int* rowds = pairs + NSTEP * 256;

    float* hb[2] = {h0, h1};
    int* lists[2] = {list0, list1};

    float* tot_h = out;
    float* ponder = out + (size_t)BATCH * HID;
    float* steps_out = ponder + 1;

    setup_kernel<<<4096, 256, 0, stream>>>(W_ih, Wp, flagcol, list0, ctrs,
                                           halt_accum, tot_rem);

    // x_base = inputs @ W_ih[:, :-1].T + b_ih   (mode 0)
    step_kernel<<<dim3(32, 8, 2), 256, 0, stream>>>(
        inputs, Wp, b_ih, nullptr, nullptr, 0.f, nullptr, nullptr, xbase,
        partials, pairx, nullptr, nullptr, nullptr, nullptr, nullptr,
        nullptr, nullptr, nullptr, nullptr, 0, 0, 0);

    for (int t = 0; t < NSTEP; t++) {
        const float* hprev = (t == 0) ? hidden : hb[(t - 1) & 1];
        step_kernel<<<dim3(32, 8, 2), 256, 0, stream>>>(
            hprev, W_hh, b_hh, xbase, flagcol, (t == 0) ? 1.f : 0.f,
            lists[t & 1], counts + t, hb[t & 1],
            partials, pairs + t * 256, rowds + t * 32,
            W_halt, b_halt, lists[(t + 1) & 1], counts + t + 1,
            halt_accum, tot_rem, tot_h, steps_out, t + 1, (t == 0) ? 1 : 0, 1);
    }
    epilogue_kernel<<<1025, 256, 0, stream>>>(hb[0], lists[1], counts + 15,
                                              halt_accum, tot_rem, tot_h, steps_out, ponder);
}

// Round 6
// 782.414 us; speedup vs baseline: 2.5551x; 2.5551x over previous
//
#include <hip/hip_runtime.h>
#include <math.h>

#define BATCH 4096
#define HID   1024
#define KDIM  1024
#define NSTEP 15
#define KV    3072      // virtual K: [A_hi·B_hi | A_hi·B_lo | A_lo·B_hi]

// MFMA GEMM: 256 threads = 4 waves; tile 128(M) x 64(N); BK=64 virtual-k.
// Wave w: rows (w&1)*64, cols (w>>1)*32; frags 4(M) x 2(N) of 16x16x32 f16.
#define TMM 128
#define TNN 64
#define LDAH 72         // LDS row stride in halfs: 144B -> 2-way max conflicts

typedef _Float16 half8 __attribute__((ext_vector_type(8)));
typedef float floatx4 __attribute__((ext_vector_type(4)));

__device__ __forceinline__ _Float16 f16hi(float x) { return (_Float16)x; }

// B3[n][kv]: kv<1024: hi(W[n][kv]); 1024..2047: lo; 2048..3071: hi (dup).
__global__ __launch_bounds__(256) void setup_kernel(
    const float* __restrict__ W_ih, const float* __restrict__ W_hh,
    _Float16* __restrict__ B3ih, _Float16* __restrict__ B3hh,
    float* __restrict__ flagcol, int* __restrict__ list0, int* __restrict__ counts,
    float* __restrict__ halt_accum, float* __restrict__ tot_rem) {
    int idx = blockIdx.x * 256 + threadIdx.x;       // grid 4096 -> 1M threads
    int n = idx >> 10, k = idx & 1023;
    {
        float w = W_hh[idx];
        _Float16 hi = f16hi(w);
        _Float16 lo = (_Float16)(w - (float)hi);
        size_t base = (size_t)n * KV;
        B3hh[base + k] = hi; B3hh[base + 1024 + k] = lo; B3hh[base + 2048 + k] = hi;
    }
    {
        float w = W_ih[(size_t)n * 1025 + k];
        _Float16 hi = f16hi(w);
        _Float16 lo = (_Float16)(w - (float)hi);
        size_t base = (size_t)n * KV;
        B3ih[base + k] = hi; B3ih[base + 1024 + k] = lo; B3ih[base + 2048 + k] = hi;
    }
    if (idx < BATCH) { list0[idx] = idx; halt_accum[idx] = 0.f; tot_rem[idx] = 0.f; }
    if (idx < KDIM) flagcol[idx] = W_ih[(size_t)idx * 1025 + 1024];
    if (idx < 16) counts[idx] = (idx == 0) ? BATCH : 0;
}

// split inputs -> (Ihi,Ilo) and hidden -> (Hhi,Hlo)
__global__ __launch_bounds__(256) void split_kernel(
    const float* __restrict__ inputs, const float* __restrict__ hidden,
    _Float16* __restrict__ Ihi, _Float16* __restrict__ Ilo,
    _Float16* __restrict__ Hhi, _Float16* __restrict__ Hlo) {
    size_t idx = (size_t)blockIdx.x * 256 + threadIdx.x;   // grid 16384 -> 4M
    float x = inputs[idx];
    _Float16 h = f16hi(x);
    Ihi[idx] = h; Ilo[idx] = (_Float16)(x - (float)h);
    float y = hidden[idx];
    _Float16 g = f16hi(y);
    Hhi[idx] = g; Hlo[idx] = (_Float16)(y - (float)g);
}

// mode 0: xout[row] = A @ B^T + bias (fp32)
// mode 1: h = tanh(acc + xbase + flag*flagcol + bias); store h fp32 + hi/lo f16
__global__ __launch_bounds__(256) void mfma_step_kernel(
    const _Float16* __restrict__ Ahi, const _Float16* __restrict__ Alo,
    const _Float16* __restrict__ B3, const float* __restrict__ bias,
    const float* __restrict__ xbase, const float* __restrict__ flagcol, float flag,
    const int* __restrict__ list, const int* __restrict__ pcount,
    float* __restrict__ hout, _Float16* __restrict__ houthi, _Float16* __restrict__ houtlo,
    float* __restrict__ xout, int mode) {
    int count = pcount ? *pcount : BATCH;
    int row0 = blockIdx.x * TMM;
    if (row0 >= count) return;
    int col0 = blockIdx.y * TNN;

    __shared__ _Float16 Asm[TMM][LDAH];
    __shared__ _Float16 Bsm[TNN][LDAH];

    int t = threadIdx.x;
    int lane = t & 63, w = t >> 6;
    int wm = (w & 1) * 64, wn = (w >> 1) * 32;

    // A staging: 128 rows x 8 halfs-quads = 1024 quads, 4/thread (gathered rows)
    int arw[4], aq8[4]; size_t aoff[4];
#pragma unroll
    for (int l = 0; l < 4; l++) {
        int q = t + l * 256;
        int r = q >> 3, qk = q & 7;
        arw[l] = r; aq8[l] = qk * 8;
        int rr = row0 + r;
        int g = (rr < count) ? (list ? list[rr] : rr) : 0;
        aoff[l] = (size_t)g * KDIM + qk * 8;
    }
    // B staging: 64 n-rows x 8 quads = 512 quads, 2/thread
    int brw[2], bq8[2]; size_t boff[2];
#pragma unroll
    for (int l = 0; l < 2; l++) {
        int q = t + l * 256;
        int r = q >> 3, qk = q & 7;
        brw[l] = r; bq8[l] = qk * 8;
        boff[l] = (size_t)(col0 + r) * KV + qk * 8;
    }

    floatx4 acc[4][2];
#pragma unroll
    for (int i = 0; i < 4; i++)
#pragma unroll
        for (int j = 0; j < 2; j++) acc[i][j] = (floatx4)(0.f);

    int l15 = lane & 15, l4 = lane >> 4;
    for (int it = 0; it < KV / 64; it++) {
        int k0v = it << 6;
        const _Float16* Asrc = (k0v < 2048) ? Ahi : Alo;   // segs [hi,hi,lo]
        int kp = k0v & 1023;
        half8 av[4], bv[2];
#pragma unroll
        for (int l = 0; l < 4; l++) av[l] = *(const half8*)(Asrc + aoff[l] + kp);
#pragma unroll
        for (int l = 0; l < 2; l++) bv[l] = *(const half8*)(B3 + boff[l] + k0v);
        __syncthreads();
#pragma unroll
        for (int l = 0; l < 4; l++) *(half8*)(&Asm[arw[l]][aq8[l]]) = av[l];
#pragma unroll
        for (int l = 0; l < 2; l++) *(half8*)(&Bsm[brw[l]][bq8[l]]) = bv[l];
        __syncthreads();
#pragma unroll
        for (int ks = 0; ks < 2; ks++) {
            int ko = ks * 32 + l4 * 8;
            half8 af[4], bf[2];
#pragma unroll
            for (int fi = 0; fi < 4; fi++)
                af[fi] = *(const half8*)(&Asm[wm + fi * 16 + l15][ko]);
#pragma unroll
            for (int fj = 0; fj < 2; fj++)
                bf[fj] = *(const half8*)(&Bsm[wn + fj * 16 + l15][ko]);
#pragma unroll
            for (int fi = 0; fi < 4; fi++)
#pragma unroll
                for (int fj = 0; fj < 2; fj++)
                    acc[fi][fj] = __builtin_amdgcn_mfma_f32_16x16x32_f16(
                        af[fi], bf[fj], acc[fi][fj], 0, 0, 0);
        }
    }

    // epilogue: C/D layout col = lane&15, row = (lane>>4)*4 + reg  [m89-verified]
#pragma unroll
    for (int fi = 0; fi < 4; fi++) {
#pragma unroll
        for (int rr = 0; rr < 4; rr++) {
            int lm = wm + fi * 16 + l4 * 4 + rr;
            int grd = row0 + lm;
            if (grd >= count) continue;
            int g = list ? list[grd] : grd;
#pragma unroll
            for (int fj = 0; fj < 2; fj++) {
                int c = col0 + wn + fj * 16 + l15;
                float v = acc[fi][fj][rr];
                if (mode == 0) {
                    xout[(size_t)g * KDIM + c] = v + bias[c];
                } else {
                    v += xbase[(size_t)g * KDIM + c] + flag * flagcol[c] + bias[c];
                    v = tanhf(v);
                    hout[(size_t)g * KDIM + c] = v;
                    _Float16 hi = f16hi(v);
                    houthi[(size_t)g * KDIM + c] = hi;
                    houtlo[(size_t)g * KDIM + c] = (_Float16)(v - (float)hi);
                }
            }
        }
    }
}

// One wave per active row: halt logit, sigmoid, halting state machine,
// tot_h accumulation into d_out, compaction of next-step list.  (R1-verified)
__global__ __launch_bounds__(256) void halt_kernel(
    const float* __restrict__ h, const float* __restrict__ W_halt,
    const float* __restrict__ b_halt,
    const int* __restrict__ list, const int* __restrict__ pcount,
    int* __restrict__ list_next, int* __restrict__ pcount_next,
    float* __restrict__ halt_accum, float* __restrict__ tot_rem,
    float* __restrict__ tot_h, float* __restrict__ steps_out,
    int stepnum, int first) {
    int count = *pcount;
    int wid = threadIdx.x >> 6, lane = threadIdx.x & 63;
    int r = blockIdx.x * 4 + wid;
    if (r >= count) return;
    int row = list[r];
    const float* hr = h + (size_t)row * HID;

    float dot = 0.f;
#pragma unroll
    for (int q = 0; q < 4; q++) {
        int c = q * 256 + lane * 4;
        float4 hv = *(const float4*)(hr + c);
        float4 wv = *(const float4*)(W_halt + c);
        dot += hv.x * wv.x + hv.y * wv.y + hv.z * wv.z + hv.w * wv.w;
    }
#pragma unroll
    for (int off = 32; off > 0; off >>= 1) dot += __shfl_down(dot, off);

    float combined = 0.f;
    if (lane == 0) {
        float p = 1.f / (1.f + expf(-(dot + b_halt[0])));
        float S = halt_accum[row] + p;
        halt_accum[row] = S;
        tot_rem[row] += p;
        bool ending = (S + p) > 0.99f;      // budget = 1 - PONDER_EPS
        if (ending) {
            combined = p + (1.f - S);
            steps_out[row] = (float)stepnum;
        } else {
            combined = p;
            int idx = atomicAdd(pcount_next, 1);
            list_next[idx] = row;
        }
    }
    combined = __shfl(combined, 0);

    float* th = tot_h + (size_t)row * HID;
#pragma unroll
    for (int q = 0; q < 4; q++) {
        int c = q * 256 + lane * 4;
        float4 hv = *(const float4*)(hr + c);
        float4 ov;
        if (first) {
            ov.x = combined * hv.x; ov.y = combined * hv.y;
            ov.z = combined * hv.z; ov.w = combined * hv.w;
        } else {
            ov = *(const float4*)(th + c);
            ov.x += combined * hv.x; ov.y += combined * hv.y;
            ov.z += combined * hv.z; ov.w += combined * hv.w;
        }
        *(float4*)(th + c) = ov;
    }
}

// blocks 0..1023: survivors get (1 - halt_accum) * h_final, steps = 16.
// block 1024: ponder reduction.
__global__ __launch_bounds__(256) void epilogue_kernel(
    const float* __restrict__ h, const int* __restrict__ list,
    const int* __restrict__ pcount, const float* __restrict__ halt_accum,
    const float* __restrict__ tot_rem,
    float* __restrict__ tot_h, float* __restrict__ steps_out,
    float* __restrict__ ponder) {
    if (blockIdx.x == 1024) {
        __shared__ float red[4];
        int t = threadIdx.x;
        float v = 0.f;
#pragma unroll
        for (int i = 0; i < 16; i++) v += tot_rem[t + i * 256];
#pragma unroll
        for (int off = 32; off > 0; off >>= 1) v += __shfl_down(v, off);
        int lane = t & 63, wid = t >> 6;
        if (lane == 0) red[wid] = v;
        __syncthreads();
        if (t == 0) ponder[0] = (red[0] + red[1] + red[2] + red[3]) * (-0.01f / 4096.f);
        return;
    }
    int count = *pcount;
    int wid = threadIdx.x >> 6, lane = threadIdx.x & 63;
    int r = blockIdx.x * 4 + wid;
    if (r >= count) return;
    int row = list[r];
    float cmb = 1.f - halt_accum[row];
    if (lane == 0) steps_out[row] = 16.f;
    const float* hr = h + (size_t)row * HID;
    float* th = tot_h + (size_t)row * HID;
#pragma unroll
    for (int q = 0; q < 4; q++) {
        int c = q * 256 + lane * 4;
        float4 hv = *(const float4*)(hr + c);
        float4 ov = *(const float4*)(th + c);
        ov.x += cmb * hv.x; ov.y += cmb * hv.y;
        ov.z += cmb * hv.z; ov.w += cmb * hv.w;
        *(float4*)(th + c) = ov;
    }
}

extern "C" void kernel_launch(void* const* d_in, const int* in_sizes, int n_in,
                              void* d_out, int out_size, void* d_ws, size_t ws_size,
                              hipStream_t stream) {
    const float* inputs = (const float*)d_in[0];
    const float* hidden = (const float*)d_in[1];
    const float* W_ih   = (const float*)d_in[2];
    const float* b_ih   = (const float*)d_in[3];
    const float* W_hh   = (const float*)d_in[4];
    const float* b_hh   = (const float*)d_in[5];
    const float* W_halt = (const float*)d_in[6];
    const float* b_halt = (const float*)d_in[7];
    float* out = (float*)d_out;

    float* ws = (float*)d_ws;
    const size_t NM = (size_t)BATCH * HID;               // 4M
    float* xbase = ws;                                   // 4M f32
    float* h     = xbase + NM;                           // 4M f32
    _Float16* B3ih = (_Float16*)(h + NM);                // 1024*3072 halfs
    _Float16* B3hh = B3ih + (size_t)HID * KV;
    _Float16* Ahi0 = B3hh + (size_t)HID * KV;            // 4M halfs each
    _Float16* Alo0 = Ahi0 + NM;
    _Float16* Ahi1 = Alo0 + NM;
    _Float16* Alo1 = Ahi1 + NM;
    float* flagcol = (float*)(Alo1 + NM);                // 1024
    float* halt_accum = flagcol + KDIM;                  // 4096
    float* tot_rem = halt_accum + BATCH;                 // 4096
    int* list0 = (int*)(tot_rem + BATCH);                // 4096
    int* list1 = list0 + BATCH;                          // 4096
    int* counts = list1 + BATCH;                         // 16

    _Float16* Ahi[2] = {Ahi0, Ahi1};
    _Float16* Alo[2] = {Alo0, Alo1};
    int* lists[2] = {list0, list1};

    float* tot_h = out;
    float* ponder = out + NM;
    float* steps_out = ponder + 1;

    setup_kernel<<<4096, 256, 0, stream>>>(W_ih, W_hh, B3ih, B3hh, flagcol,
                                           list0, counts, halt_accum, tot_rem);
    // inputs split -> buf1 (dead after x_base; step0 re-writes buf1), hidden -> buf0
    split_kernel<<<16384, 256, 0, stream>>>(inputs, hidden, Ahi1, Alo1, Ahi0, Alo0);

    // x_base = inputs @ W_ih[:, :-1].T + b_ih
    mfma_step_kernel<<<dim3(32, 16), 256, 0, stream>>>(
        Ahi1, Alo1, B3ih, b_ih, nullptr, nullptr, 0.f, nullptr, nullptr,
        nullptr, nullptr, nullptr, xbase, 0);

    for (int t = 0; t < NSTEP; t++) {
        mfma_step_kernel<<<dim3(32, 16), 256, 0, stream>>>(
            Ahi[t & 1], Alo[t & 1], B3hh, b_hh, xbase, flagcol,
            (t == 0) ? 1.f : 0.f, lists[t & 1], counts + t,
            h, Ahi[(t + 1) & 1], Alo[(t + 1) & 1], nullptr, 1);
        halt_kernel<<<1024, 256, 0, stream>>>(h, W_halt, b_halt,
                                              lists[t & 1], counts + t,
                                              lists[(t + 1) & 1], counts + t + 1,
                                              halt_accum, tot_rem, tot_h, steps_out,
                                              t + 1, (t == 0) ? 1 : 0);
    }
    epilogue_kernel<<<1025, 256, 0, stream>>>(h, lists[1], counts + 15,
                                              halt_accum, tot_rem, tot_h, steps_out, ponder);
}

// Round 7
// 736.584 us; speedup vs baseline: 2.7140x; 1.0622x over previous
//
#include <hip/hip_runtime.h>
#include <math.h>

#define BATCH 4096
#define HID   1024
#define KDIM  1024
#define NSTEP 15
#define KV    3072      // virtual K: [A_hi·B_hi | A_hi·B_lo | A_lo·B_hi]
#define NCHUNK (KV / 64)

// MFMA GEMM: 256 threads = 4 waves; tile 128(M) x 64(N); BK=64 virtual-k.
// Wave w: rows (w&1)*64, cols (w>>1)*32; frags 4(M) x 2(N) of 16x16x32 f16.
// Double-buffered LDS + register prefetch: one barrier per chunk.
#define TMM 128
#define TNN 64
#define LDAH 72         // LDS row stride in halfs (144B)

typedef _Float16 half8 __attribute__((ext_vector_type(8)));
typedef float floatx4 __attribute__((ext_vector_type(4)));

__device__ __forceinline__ _Float16 f16hi(float x) { return (_Float16)x; }

// B3[n][kv]: kv<1024: hi(W[n][kv]); 1024..2047: lo; 2048..3071: hi (dup).
// Also: split inputs/hidden into f16 hi/lo, init lists/accums.
__global__ __launch_bounds__(256) void setup_kernel(
    const float* __restrict__ W_ih, const float* __restrict__ W_hh,
    const float* __restrict__ inputs, const float* __restrict__ hidden,
    _Float16* __restrict__ B3ih, _Float16* __restrict__ B3hh,
    _Float16* __restrict__ Ihi, _Float16* __restrict__ Ilo,
    _Float16* __restrict__ Hhi, _Float16* __restrict__ Hlo,
    float* __restrict__ flagcol, int* __restrict__ list0, int* __restrict__ counts,
    float* __restrict__ halt_accum, float* __restrict__ tot_rem) {
    size_t idx = (size_t)blockIdx.x * 256 + threadIdx.x;   // grid 16384 -> 4M
    {   // split inputs -> I, hidden -> H
        float x = inputs[idx];
        _Float16 h = f16hi(x);
        Ihi[idx] = h; Ilo[idx] = (_Float16)(x - (float)h);
        float y = hidden[idx];
        _Float16 g = f16hi(y);
        Hhi[idx] = g; Hlo[idx] = (_Float16)(y - (float)g);
    }
    if (idx < (size_t)KDIM * KDIM) {
        int n = (int)(idx >> 10), k = (int)(idx & 1023);
        float w = W_hh[idx];
        _Float16 hi = f16hi(w);
        _Float16 lo = (_Float16)(w - (float)hi);
        size_t base = (size_t)n * KV;
        B3hh[base + k] = hi; B3hh[base + 1024 + k] = lo; B3hh[base + 2048 + k] = hi;
        float w2 = W_ih[(size_t)n * 1025 + k];
        _Float16 hi2 = f16hi(w2);
        _Float16 lo2 = (_Float16)(w2 - (float)hi2);
        B3ih[base + k] = hi2; B3ih[base + 1024 + k] = lo2; B3ih[base + 2048 + k] = hi2;
    }
    if (idx < BATCH) { list0[idx] = idx; halt_accum[idx] = 0.f; tot_rem[idx] = 0.f; }
    if (idx < KDIM) flagcol[idx] = W_ih[idx * 1025 + 1024];
    if (idx < 16) counts[idx] = (idx == 0) ? BATCH : 0;
}

// mode 0: xout[row] = A @ B^T + bias (fp32)
// mode 1: h = tanh(acc + xbase + flag*flagcol + bias); store h fp32 + hi/lo f16
__global__ __launch_bounds__(256) void mfma_step_kernel(
    const _Float16* __restrict__ Ahi, const _Float16* __restrict__ Alo,
    const _Float16* __restrict__ B3, const float* __restrict__ bias,
    const float* __restrict__ xbase, const float* __restrict__ flagcol, float flag,
    const int* __restrict__ list, const int* __restrict__ pcount,
    float* __restrict__ hout, _Float16* __restrict__ houthi, _Float16* __restrict__ houtlo,
    float* __restrict__ xout, int mode) {
    int count = pcount ? *pcount : BATCH;
    int row0 = blockIdx.x * TMM;
    if (row0 >= count) return;
    int col0 = blockIdx.y * TNN;

    __shared__ _Float16 Asm[2][TMM][LDAH];
    __shared__ _Float16 Bsm[2][TNN][LDAH];

    int t = threadIdx.x;
    int lane = t & 63, w = t >> 6;
    int wm = (w & 1) * 64, wn = (w >> 1) * 32;

    // A staging: 128 rows x 8 half8-quads = 1024 quads, 4/thread (gathered rows)
    int arw[4], aq8[4]; size_t aoff[4];
#pragma unroll
    for (int l = 0; l < 4; l++) {
        int q = t + l * 256;
        int r = q >> 3, qk = q & 7;
        arw[l] = r; aq8[l] = qk * 8;
        int rr = row0 + r;
        int g = (rr < count) ? (list ? list[rr] : rr) : 0;
        aoff[l] = (size_t)g * KDIM + qk * 8;
    }
    // B staging: 64 n-rows x 8 quads = 512 quads, 2/thread
    int brw[2], bq8[2]; size_t boff[2];
#pragma unroll
    for (int l = 0; l < 2; l++) {
        int q = t + l * 256;
        int r = q >> 3, qk = q & 7;
        brw[l] = r; bq8[l] = qk * 8;
        boff[l] = (size_t)(col0 + r) * KV + qk * 8;
    }

    floatx4 acc[4][2];
#pragma unroll
    for (int i = 0; i < 4; i++)
#pragma unroll
        for (int j = 0; j < 2; j++) acc[i][j] = (floatx4)(0.f);

    int l15 = lane & 15, l4 = lane >> 4;

    // preload chunk 0 (k0v=0 -> Ahi, kp=0) into buf 0
    half8 av[4], bv[2];
#pragma unroll
    for (int l = 0; l < 4; l++) av[l] = *(const half8*)(Ahi + aoff[l]);
#pragma unroll
    for (int l = 0; l < 2; l++) bv[l] = *(const half8*)(B3 + boff[l]);
#pragma unroll
    for (int l = 0; l < 4; l++) *(half8*)(&Asm[0][arw[l]][aq8[l]]) = av[l];
#pragma unroll
    for (int l = 0; l < 2; l++) *(half8*)(&Bsm[0][brw[l]][bq8[l]]) = bv[l];
    __syncthreads();

    int p = 0;
    for (int it = 0; it < NCHUNK; it++) {
        // issue global prefetch for chunk it+1 (overlaps with MFMA below)
        if (it + 1 < NCHUNK) {
            int k0v = (it + 1) << 6;
            const _Float16* Asrc = (k0v < 2048) ? Ahi : Alo;   // segs [hi,hi,lo]
            int kp = k0v & 1023;
#pragma unroll
            for (int l = 0; l < 4; l++) av[l] = *(const half8*)(Asrc + aoff[l] + kp);
#pragma unroll
            for (int l = 0; l < 2; l++) bv[l] = *(const half8*)(B3 + boff[l] + k0v);
        }
        // MFMA from buf p
#pragma unroll
        for (int ks = 0; ks < 2; ks++) {
            int ko = ks * 32 + l4 * 8;
            half8 af[4], bf[2];
#pragma unroll
            for (int fi = 0; fi < 4; fi++)
                af[fi] = *(const half8*)(&Asm[p][wm + fi * 16 + l15][ko]);
#pragma unroll
            for (int fj = 0; fj < 2; fj++)
                bf[fj] = *(const half8*)(&Bsm[p][wn + fj * 16 + l15][ko]);
#pragma unroll
            for (int fi = 0; fi < 4; fi++)
#pragma unroll
                for (int fj = 0; fj < 2; fj++)
                    acc[fi][fj] = __builtin_amdgcn_mfma_f32_16x16x32_f16(
                        af[fi], bf[fj], acc[fi][fj], 0, 0, 0);
        }
        // write prefetch to buf p^1
        if (it + 1 < NCHUNK) {
            int q = p ^ 1;
#pragma unroll
            for (int l = 0; l < 4; l++) *(half8*)(&Asm[q][arw[l]][aq8[l]]) = av[l];
#pragma unroll
            for (int l = 0; l < 2; l++) *(half8*)(&Bsm[q][brw[l]][bq8[l]]) = bv[l];
        }
        __syncthreads();
        p ^= 1;
    }

    // epilogue: C/D layout col = lane&15, row = (lane>>4)*4 + reg  [m89-verified]
#pragma unroll
    for (int fi = 0; fi < 4; fi++) {
#pragma unroll
        for (int rr = 0; rr < 4; rr++) {
            int lm = wm + fi * 16 + l4 * 4 + rr;
            int grd = row0 + lm;
            if (grd >= count) continue;
            int g = list ? list[grd] : grd;
#pragma unroll
            for (int fj = 0; fj < 2; fj++) {
                int c = col0 + wn + fj * 16 + l15;
                float v = acc[fi][fj][rr];
                if (mode == 0) {
                    xout[(size_t)g * KDIM + c] = v + bias[c];
                } else {
                    v += xbase[(size_t)g * KDIM + c] + flag * flagcol[c] + bias[c];
                    v = tanhf(v);
                    hout[(size_t)g * KDIM + c] = v;
                    _Float16 hi = f16hi(v);
                    houthi[(size_t)g * KDIM + c] = hi;
                    houtlo[(size_t)g * KDIM + c] = (_Float16)(v - (float)hi);
                }
            }
        }
    }
}

// One wave per active row: halt logit, sigmoid, halting state machine,
// tot_h accumulation into d_out, compaction of next-step list.  (R1-verified)
__global__ __launch_bounds__(256) void halt_kernel(
    const float* __restrict__ h, const float* __restrict__ W_halt,
    const float* __restrict__ b_halt,
    const int* __restrict__ list, const int* __restrict__ pcount,
    int* __restrict__ list_next, int* __restrict__ pcount_next,
    float* __restrict__ halt_accum, float* __restrict__ tot_rem,
    float* __restrict__ tot_h, float* __restrict__ steps_out,
    int stepnum, int first) {
    int count = *pcount;
    int wid = threadIdx.x >> 6, lane = threadIdx.x & 63;
    int r = blockIdx.x * 4 + wid;
    if (r >= count) return;
    int row = list[r];
    const float* hr = h + (size_t)row * HID;

    float dot = 0.f;
#pragma unroll
    for (int q = 0; q < 4; q++) {
        int c = q * 256 + lane * 4;
        float4 hv = *(const float4*)(hr + c);
        float4 wv = *(const float4*)(W_halt + c);
        dot += hv.x * wv.x + hv.y * wv.y + hv.z * wv.z + hv.w * wv.w;
    }
#pragma unroll
    for (int off = 32; off > 0; off >>= 1) dot += __shfl_down(dot, off);

    float combined = 0.f;
    if (lane == 0) {
        float p = 1.f / (1.f + expf(-(dot + b_halt[0])));
        float S = halt_accum[row] + p;
        halt_accum[row] = S;
        tot_rem[row] += p;
        bool ending = (S + p) > 0.99f;      // budget = 1 - PONDER_EPS
        if (ending) {
            combined = p + (1.f - S);
            steps_out[row] = (float)stepnum;
        } else {
            combined = p;
            int idx = atomicAdd(pcount_next, 1);
            list_next[idx] = row;
        }
    }
    combined = __shfl(combined, 0);

    float* th = tot_h + (size_t)row * HID;
#pragma unroll
    for (int q = 0; q < 4; q++) {
        int c = q * 256 + lane * 4;
        float4 hv = *(const float4*)(hr + c);
        float4 ov;
        if (first) {
            ov.x = combined * hv.x; ov.y = combined * hv.y;
            ov.z = combined * hv.z; ov.w = combined * hv.w;
        } else {
            ov = *(const float4*)(th + c);
            ov.x += combined * hv.x; ov.y += combined * hv.y;
            ov.z += combined * hv.z; ov.w += combined * hv.w;
        }
        *(float4*)(th + c) = ov;
    }
}

// blocks 0..1023: survivors get (1 - halt_accum) * h_final, steps = 16.
// block 1024: ponder reduction.
__global__ __launch_bounds__(256) void epilogue_kernel(
    const float* __restrict__ h, const int* __restrict__ list,
    const int* __restrict__ pcount, const float* __restrict__ halt_accum,
    const float* __restrict__ tot_rem,
    float* __restrict__ tot_h, float* __restrict__ steps_out,
    float* __restrict__ ponder) {
    if (blockIdx.x == 1024) {
        __shared__ float red[4];
        int t = threadIdx.x;
        float v = 0.f;
#pragma unroll
        for (int i = 0; i < 16; i++) v += tot_rem[t + i * 256];
#pragma unroll
        for (int off = 32; off > 0; off >>= 1) v += __shfl_down(v, off);
        int lane = t & 63, wid = t >> 6;
        if (lane == 0) red[wid] = v;
        __syncthreads();
        if (t == 0) ponder[0] = (red[0] + red[1] + red[2] + red[3]) * (-0.01f / 4096.f);
        return;
    }
    int count = *pcount;
    int wid = threadIdx.x >> 6, lane = threadIdx.x & 63;
    int r = blockIdx.x * 4 + wid;
    if (r >= count) return;
    int row = list[r];
    float cmb = 1.f - halt_accum[row];
    if (lane == 0) steps_out[row] = 16.f;
    const float* hr = h + (size_t)row * HID;
    float* th = tot_h + (size_t)row * HID;
#pragma unroll
    for (int q = 0; q < 4; q++) {
        int c = q * 256 + lane * 4;
        float4 hv = *(const float4*)(hr + c);
        float4 ov = *(const float4*)(th + c);
        ov.x += cmb * hv.x; ov.y += cmb * hv.y;
        ov.z += cmb * hv.z; ov.w += cmb * hv.w;
        *(float4*)(th + c) = ov;
    }
}

extern "C" void kernel_launch(void* const* d_in, const int* in_sizes, int n_in,
                              void* d_out, int out_size, void* d_ws, size_t ws_size,
                              hipStream_t stream) {
    const float* inputs = (const float*)d_in[0];
    const float* hidden = (const float*)d_in[1];
    const float* W_ih   = (const float*)d_in[2];
    const float* b_ih   = (const float*)d_in[3];
    const float* W_hh   = (const float*)d_in[4];
    const float* b_hh   = (const float*)d_in[5];
    const float* W_halt = (const float*)d_in[6];
    const float* b_halt = (const float*)d_in[7];
    float* out = (float*)d_out;

    float* ws = (float*)d_ws;
    const size_t NM = (size_t)BATCH * HID;               // 4M
    float* xbase = ws;                                   // 4M f32
    float* h     = xbase + NM;                           // 4M f32
    _Float16* B3ih = (_Float16*)(h + NM);                // 1024*3072 halfs
    _Float16* B3hh = B3ih + (size_t)HID * KV;
    _Float16* Ahi0 = B3hh + (size_t)HID * KV;            // 4M halfs each
    _Float16* Alo0 = Ahi0 + NM;
    _Float16* Ahi1 = Alo0 + NM;
    _Float16* Alo1 = Ahi1 + NM;
    float* flagcol = (float*)(Alo1 + NM);                // 1024
    float* halt_accum = flagcol + KDIM;                  // 4096
    float* tot_rem = halt_accum + BATCH;                 // 4096
    int* list0 = (int*)(tot_rem + BATCH);                // 4096
    int* list1 = list0 + BATCH;                          // 4096
    int* counts = list1 + BATCH;                         // 16

    _Float16* Ahi[2] = {Ahi0, Ahi1};
    _Float16* Alo[2] = {Alo0, Alo1};
    int* lists[2] = {list0, list1};

    float* tot_h = out;
    float* ponder = out + NM;
    float* steps_out = ponder + 1;

    // setup + split fused: inputs -> buf1 (dead after x_base), hidden -> buf0
    setup_kernel<<<16384, 256, 0, stream>>>(W_ih, W_hh, inputs, hidden,
                                            B3ih, B3hh, Ahi1, Alo1, Ahi0, Alo0,
                                            flagcol, list0, counts, halt_accum, tot_rem);

    // x_base = inputs @ W_ih[:, :-1].T + b_ih
    mfma_step_kernel<<<dim3(32, 16), 256, 0, stream>>>(
        Ahi1, Alo1, B3ih, b_ih, nullptr, nullptr, 0.f, nullptr, nullptr,
        nullptr, nullptr, nullptr, xbase, 0);

    for (int t = 0; t < NSTEP; t++) {
        mfma_step_kernel<<<dim3(32, 16), 256, 0, stream>>>(
            Ahi[t & 1], Alo[t & 1], B3hh, b_hh, xbase, flagcol,
            (t == 0) ? 1.f : 0.f, lists[t & 1], counts + t,
            h, Ahi[(t + 1) & 1], Alo[(t + 1) & 1], nullptr, 1);
        halt_kernel<<<1024, 256, 0, stream>>>(h, W_halt, b_halt,
                                              lists[t & 1], counts + t,
                                              lists[(t + 1) & 1], counts + t + 1,
                                              halt_accum, tot_rem, tot_h, steps_out,
                                              t + 1, (t == 0) ? 1 : 0);
    }
    epilogue_kernel<<<1025, 256, 0, stream>>>(h, lists[1], counts + 15,
                                              halt_accum, tot_rem, tot_h, steps_out, ponder);
}